// Round 10
// baseline (276.224 us; speedup 1.0000x reference)
//
#include <hip/hip_runtime.h>

#define NN 50000
#define NE 800000
#define DIN 256
#define DH 128
#define BCAP 64

// merged prep+gemm grid layout
#define GEMM_BLKS 391   // ceil(NN/128) rows of gemm
#define SWZ_BLKS 32     // weight pre-swizzle
#define FILL_BLKS (NE / 256)

typedef float f32x4 __attribute__((ext_vector_type(4)));
typedef __bf16 bf16x8 __attribute__((ext_vector_type(8)));
typedef unsigned short u16;
typedef unsigned int u32;

__device__ __forceinline__ u16 f2b(float f) { return __builtin_bit_cast(u16, (__bf16)f); }
__device__ __forceinline__ float lo_f(u32 u) { return (float)__builtin_bit_cast(__bf16, (u16)(u & 0xFFFFu)); }
__device__ __forceinline__ float hi_f(u32 u) { return (float)__builtin_bit_cast(__bf16, (u16)(u >> 16)); }

__device__ __forceinline__ f32x4 mfma16(bf16x8 a, bf16x8 b, f32x4 c) {
    return __builtin_amdgcn_mfma_f32_16x16x32_bf16(a, b, c, 0, 0, 0);
}

// ---------------- merged: gemm (h0pre = x @ W_gcn, UNSCALED) + weight swizzle + bucket fill ----
__global__ __launch_bounds__(256) void k_prep_gemm(const float* __restrict__ x,
                                                   const float* __restrict__ w1,
                                                   const float* __restrict__ w2,
                                                   const float* __restrict__ wg,
                                                   u16* __restrict__ w12f, u16* __restrict__ wgf,
                                                   const int* __restrict__ ei,
                                                   int* __restrict__ cnt, int* __restrict__ bucket,
                                                   u16* __restrict__ h0pre) {
    int b = blockIdx.x;
    if (b < GEMM_BLKS) {
        // ---- gemm part: 128 rows/block, 4 waves x 32 rows ----
        int wave = threadIdx.x >> 6, lane = threadIdx.x & 63;
        int l15 = lane & 15, q = lane >> 4;
        int rowBase = b * 128 + wave * 32;

        bf16x8 a[2][8];
#pragma unroll
        for (int mi = 0; mi < 2; ++mi) {
            int r = rowBase + mi * 16 + l15; if (r >= NN) r = NN - 1;
            const float* rp = x + (size_t)r * DIN + q * 8;
#pragma unroll
            for (int kt = 0; kt < 8; ++kt) {
                f32x4 f0 = *(const f32x4*)(rp + kt * 32);
                f32x4 f1 = *(const f32x4*)(rp + kt * 32 + 4);
                bf16x8 aa;
#pragma unroll
                for (int j = 0; j < 4; ++j) { aa[j] = (__bf16)f0[j]; aa[j + 4] = (__bf16)f1[j]; }
                a[mi][kt] = aa;
            }
        }
        f32x4 z = {0.f, 0.f, 0.f, 0.f};
        f32x4 acc[2][8];
#pragma unroll
        for (int mi = 0; mi < 2; ++mi)
#pragma unroll
            for (int nt = 0; nt < 8; ++nt) acc[mi][nt] = z;
#pragma unroll
        for (int kt = 0; kt < 8; ++kt)
#pragma unroll
            for (int nt = 0; nt < 8; ++nt) {
                bf16x8 bb = *(const bf16x8*)(wgf + ((kt * 8 + nt) * 64 + lane) * 8);
                acc[0][nt] = mfma16(a[0][kt], bb, acc[0][nt]);
                acc[1][nt] = mfma16(a[1][kt], bb, acc[1][nt]);
            }
#pragma unroll
        for (int mi = 0; mi < 2; ++mi)
#pragma unroll
            for (int rg = 0; rg < 4; ++rg) {
                int r = rowBase + mi * 16 + q * 4 + rg;
                if (r < NN) {
#pragma unroll
                    for (int nt = 0; nt < 8; ++nt)
                        h0pre[r * DH + nt * 16 + l15] = f2b(acc[mi][nt][rg]);
                }
            }
    } else if (b < GEMM_BLKS + SWZ_BLKS) {
        // ---- weight pre-swizzle: 8192 threads total ----
        int t = (b - GEMM_BLKS) * 256 + threadIdx.x;
        const float* src; u16* dst; int id;
        if (t < 2048)      { src = w1; dst = w12f;          id = t; }
        else if (t < 4096) { src = w2; dst = w12f + 16384;  id = t - 2048; }
        else               { src = wg; dst = wgf;           id = t - 4096; }
        int lane = id & 63, frag = id >> 6;
        int kt = frag >> 3, nt = frag & 7;
        int k0 = kt * 32 + (lane >> 4) * 8, n = nt * 16 + (lane & 15);
        u16 v[8];
#pragma unroll
        for (int j = 0; j < 8; ++j) v[j] = f2b(src[(k0 + j) * 128 + n]);
#pragma unroll
        for (int j = 0; j < 8; ++j) dst[id * 8 + j] = v[j];
    } else {
        // ---- bucket fill ----
        int e = (b - GEMM_BLKS - SWZ_BLKS) * 256 + threadIdx.x;
        int d = ei[NE + e];
        int pos = atomicAdd(&cnt[d], 1);
        bucket[d * BCAP + pos] = ei[e];
    }
}

// ---------------- FUSED aggregate + node MLP v2: barrier-free ----------------
// Each wave independently: aggregate its own 16 nodes (quarter-wave/node, uint4 gathers)
// into per-wave LDS scratch, then run the 3-layer MLP on those 16 rows with B-fragments
// read DIRECTLY FROM GLOBAL w12f (L2-resident 64KB, same pattern as k_prep_gemm's wgf).
// Zero __syncthreads -> no inter-wave coupling (the R5-fusion failure mode), no hA
// round-trip, one fewer launch. LDS = 17.4 KB/block only.
// gh = 0.5 * (relu(relu(hA@W1+b1)@W2+b2) @ W1) + 0.5*b1
__global__ __launch_bounds__(256) void k_agg_mlp(const u16* __restrict__ h0pre,
                                                 const int* __restrict__ cnt,
                                                 const int* __restrict__ bucket,
                                                 const float* __restrict__ bg,
                                                 const u16* __restrict__ wf,
                                                 const float* __restrict__ b1,
                                                 const float* __restrict__ b2,
                                                 u16* __restrict__ gh) {
    __shared__ __align__(16) u16 sct[4][2176];    // per-wave: agg rows [16][136] / transpose scratch
    int wave = threadIdx.x >> 6, lane = threadIdx.x & 63;
    int qw = lane >> 4, l16 = lane & 15;
    const uint4* h4p = (const uint4*)h0pre;
    u16* sw = sct[wave];
    int rowBase = blockIdx.x * 64 + wave * 16;

    // ---- phase A: aggregate 16 nodes (4 passes x 4 nodes, quarter-wave each; proven R4/R5 body)
#pragma unroll 1
    for (int p = 0; p < 4; ++p) {
        int vl = p * 4 + qw;                         // local row 0..15
        int v = rowBase + vl;
        if (v >= NN) v = NN - 1;                     // dup work, guarded at gh write

        int deg = cnt[v];
        float dv = rsqrtf((float)deg + 1.0f);
        uint4 su = h4p[v * 16 + l16];
        float acc0[8], acc1[8];
#pragma unroll
        for (int i = 0; i < 8; ++i) acc1[i] = 0.f;
        acc0[0] = lo_f(su.x) * dv; acc0[1] = hi_f(su.x) * dv;
        acc0[2] = lo_f(su.y) * dv; acc0[3] = hi_f(su.y) * dv;
        acc0[4] = lo_f(su.z) * dv; acc0[5] = hi_f(su.z) * dv;
        acc0[6] = lo_f(su.w) * dv; acc0[7] = hi_f(su.w) * dv;

        const int* bk = bucket + v * BCAP;
        int j = 0;
        for (; j + 8 <= deg; j += 8) {
            int idx[8]; uint4 u[8]; float ds[8];
#pragma unroll
            for (int k = 0; k < 8; ++k) idx[k] = bk[j + k];
#pragma unroll
            for (int k = 0; k < 8; ++k) u[k] = h4p[idx[k] * 16 + l16];
#pragma unroll
            for (int k = 0; k < 8; ++k) ds[k] = rsqrtf((float)cnt[idx[k]] + 1.0f);
#pragma unroll
            for (int k = 0; k < 8; ++k) {
                float* A = (k & 1) ? acc1 : acc0;
                A[0] = fmaf(lo_f(u[k].x), ds[k], A[0]);
                A[1] = fmaf(hi_f(u[k].x), ds[k], A[1]);
                A[2] = fmaf(lo_f(u[k].y), ds[k], A[2]);
                A[3] = fmaf(hi_f(u[k].y), ds[k], A[3]);
                A[4] = fmaf(lo_f(u[k].z), ds[k], A[4]);
                A[5] = fmaf(hi_f(u[k].z), ds[k], A[5]);
                A[6] = fmaf(lo_f(u[k].w), ds[k], A[6]);
                A[7] = fmaf(hi_f(u[k].w), ds[k], A[7]);
            }
        }
        for (; j + 2 <= deg; j += 2) {
            int ia = bk[j], ib = bk[j + 1];
            uint4 ua = h4p[ia * 16 + l16];
            uint4 ub = h4p[ib * 16 + l16];
            float da = rsqrtf((float)cnt[ia] + 1.0f);
            float db = rsqrtf((float)cnt[ib] + 1.0f);
            acc0[0] = fmaf(lo_f(ua.x), da, acc0[0]); acc0[1] = fmaf(hi_f(ua.x), da, acc0[1]);
            acc0[2] = fmaf(lo_f(ua.y), da, acc0[2]); acc0[3] = fmaf(hi_f(ua.y), da, acc0[3]);
            acc0[4] = fmaf(lo_f(ua.z), da, acc0[4]); acc0[5] = fmaf(hi_f(ua.z), da, acc0[5]);
            acc0[6] = fmaf(lo_f(ua.w), da, acc0[6]); acc0[7] = fmaf(hi_f(ua.w), da, acc0[7]);
            acc1[0] = fmaf(lo_f(ub.x), db, acc1[0]); acc1[1] = fmaf(hi_f(ub.x), db, acc1[1]);
            acc1[2] = fmaf(lo_f(ub.y), db, acc1[2]); acc1[3] = fmaf(hi_f(ub.y), db, acc1[3]);
            acc1[4] = fmaf(lo_f(ub.z), db, acc1[4]); acc1[5] = fmaf(hi_f(ub.z), db, acc1[5]);
            acc1[6] = fmaf(lo_f(ub.w), db, acc1[6]); acc1[7] = fmaf(hi_f(ub.w), db, acc1[7]);
        }
        for (; j < deg; ++j) {
            int ia = bk[j];
            uint4 u = h4p[ia * 16 + l16];
            float da = rsqrtf((float)cnt[ia] + 1.0f);
            acc0[0] = fmaf(lo_f(u.x), da, acc0[0]); acc0[1] = fmaf(hi_f(u.x), da, acc0[1]);
            acc0[2] = fmaf(lo_f(u.y), da, acc0[2]); acc0[3] = fmaf(hi_f(u.y), da, acc0[3]);
            acc0[4] = fmaf(lo_f(u.z), da, acc0[4]); acc0[5] = fmaf(hi_f(u.z), da, acc0[5]);
            acc0[6] = fmaf(lo_f(u.w), da, acc0[6]); acc0[7] = fmaf(hi_f(u.w), da, acc0[7]);
        }
        float4 bg0 = ((const float4*)bg)[l16 * 2];
        float4 bg1 = ((const float4*)bg)[l16 * 2 + 1];
        float r[8];
#pragma unroll
        for (int i = 0; i < 8; ++i) r[i] = acc0[i] + acc1[i];
        r[0] = fmaxf(r[0] * dv + bg0.x, 0.f); r[1] = fmaxf(r[1] * dv + bg0.y, 0.f);
        r[2] = fmaxf(r[2] * dv + bg0.z, 0.f); r[3] = fmaxf(r[3] * dv + bg0.w, 0.f);
        r[4] = fmaxf(r[4] * dv + bg1.x, 0.f); r[5] = fmaxf(r[5] * dv + bg1.y, 0.f);
        r[6] = fmaxf(r[6] * dv + bg1.z, 0.f); r[7] = fmaxf(r[7] * dv + bg1.w, 0.f);
        uint4 outw;
        outw.x = (u32)f2b(r[0]) | ((u32)f2b(r[1]) << 16);
        outw.y = (u32)f2b(r[2]) | ((u32)f2b(r[3]) << 16);
        outw.z = (u32)f2b(r[4]) | ((u32)f2b(r[5]) << 16);
        outw.w = (u32)f2b(r[6]) | ((u32)f2b(r[7]) << 16);
        *(uint4*)(sw + vl * 136 + l16 * 8) = outw;   // row vl, channels l16*8..+7
    }

    // ---- phase B: 3-layer MLP on own 16 rows; B-fragments straight from global (no barriers)
    int l15 = lane & 15, q = lane >> 4;
    float bb1[8], bb2[8];
#pragma unroll
    for (int nt = 0; nt < 8; ++nt) { bb1[nt] = b1[nt * 16 + l15]; bb2[nt] = b2[nt * 16 + l15]; }

    bf16x8 a[4];
#pragma unroll
    for (int kt = 0; kt < 4; ++kt) a[kt] = *(const bf16x8*)(sw + l15 * 136 + kt * 32 + q * 8);
    f32x4 z = {0.f, 0.f, 0.f, 0.f};
    f32x4 acc1[8];
#pragma unroll
    for (int nt = 0; nt < 8; ++nt) acc1[nt] = z;
#pragma unroll
    for (int kt = 0; kt < 4; ++kt)
#pragma unroll
        for (int nt = 0; nt < 8; ++nt) {
            bf16x8 b = *(const bf16x8*)(wf + (kt * 8 + nt) * 512 + lane * 8);          // W1
            acc1[nt] = mfma16(a[kt], b, acc1[nt]);
        }

    bf16x8 a2[4];
#pragma unroll
    for (int nt = 0; nt < 8; ++nt)
#pragma unroll
        for (int rg = 0; rg < 4; ++rg) {
            float v = acc1[nt][rg] + bb1[nt];
            v = v > 0.f ? v : 0.f;
            sw[(q * 4 + rg) * 136 + nt * 16 + l15] = f2b(v);
        }
#pragma unroll
    for (int kt = 0; kt < 4; ++kt)
        a2[kt] = *(const bf16x8*)(sw + l15 * 136 + kt * 32 + q * 8);

    f32x4 acc2[8];
#pragma unroll
    for (int nt = 0; nt < 8; ++nt) acc2[nt] = z;
#pragma unroll
    for (int kt = 0; kt < 4; ++kt)
#pragma unroll
        for (int nt = 0; nt < 8; ++nt) {
            bf16x8 b = *(const bf16x8*)(wf + 16384 + (kt * 8 + nt) * 512 + lane * 8);  // W2
            acc2[nt] = mfma16(a2[kt], b, acc2[nt]);
        }
    bf16x8 a3[4];
#pragma unroll
    for (int nt = 0; nt < 8; ++nt)
#pragma unroll
        for (int rg = 0; rg < 4; ++rg) {
            float v = acc2[nt][rg] + bb2[nt];
            v = v > 0.f ? v : 0.f;
            sw[(q * 4 + rg) * 136 + nt * 16 + l15] = f2b(v);
        }
#pragma unroll
    for (int kt = 0; kt < 4; ++kt)
        a3[kt] = *(const bf16x8*)(sw + l15 * 136 + kt * 32 + q * 8);

    f32x4 acc3[8];
#pragma unroll
    for (int nt = 0; nt < 8; ++nt) acc3[nt] = z;
#pragma unroll
    for (int kt = 0; kt < 4; ++kt)
#pragma unroll
        for (int nt = 0; nt < 8; ++nt) {
            bf16x8 b = *(const bf16x8*)(wf + (kt * 8 + nt) * 512 + lane * 8);          // W1 again
            acc3[nt] = mfma16(a3[kt], b, acc3[nt]);
        }
#pragma unroll
    for (int nt = 0; nt < 8; ++nt)
#pragma unroll
        for (int rg = 0; rg < 4; ++rg) {
            int r = rowBase + q * 4 + rg;
            if (r < NN)
                gh[r * DH + nt * 16 + l15] = f2b(0.5f * acc3[nt][rg] + 0.5f * bb1[nt]);
        }
}

// ---------------- edge kernel (exact R9 proven version): single prefetch buffer, 4 blocks/CU ----
__global__ __launch_bounds__(256, 4) void k_edge_mlp(const u16* __restrict__ gh,
                                                     const int* __restrict__ ei,
                                                     const u16* __restrict__ wf,
                                                     const float* __restrict__ b2,
                                                     const float* __restrict__ ow,
                                                     const float* __restrict__ ob,
                                                     float2* __restrict__ outp) {
    __shared__ __align__(16) u16 wlds[16384];  // W2 only
    {
        const uint4* s = (const uint4*)(wf + 16384);
        uint4* d = (uint4*)wlds;
        for (int i = threadIdx.x; i < 2048; i += 256) d[i] = s[i];
    }
    int wave = threadIdx.x >> 6, lane = threadIdx.x & 63;
    int l15 = lane & 15, q = lane >> 4;
    int eBase = blockIdx.x * 256 + wave * 64;

    int se[4], de[4];
#pragma unroll
    for (int ti = 0; ti < 4; ++ti) {
        int e = eBase + ti * 16 + l15;
        se[ti] = ei[e];
        de[ti] = ei[NE + e];
    }
    // prefetch tile 0 into the single buffer
    bf16x8 bs[4], bd[4];
    {
        const u16* ps = gh + se[0] * DH + q * 8;
        const u16* pd = gh + de[0] * DH + q * 8;
#pragma unroll
        for (int kt = 0; kt < 4; ++kt) {
            bs[kt] = *(const bf16x8*)(ps + kt * 32);
            bd[kt] = *(const bf16x8*)(pd + kt * 32);
        }
    }
    float bb2[8], owp0[8], owp1[8];
#pragma unroll
    for (int nt = 0; nt < 8; ++nt) {
        int k = nt * 16 + l15;
        bb2[nt] = b2[k];
        owp0[nt] = ow[2 * k];
        owp1[nt] = ow[2 * k + 1];
    }
    float ob0 = ob[0], ob1 = ob[1];
    __syncthreads();  // W2 staged (tile-0 gathers already in flight)
    f32x4 z = {0.f, 0.f, 0.f, 0.f};

#pragma unroll
    for (int ti = 0; ti < 4; ++ti) {
        // t1 = relu(gh_s + gh_d): consumes the buffer into A-fragment layout
        bf16x8 a2[4];
#pragma unroll
        for (int kt = 0; kt < 4; ++kt) {
            bf16x8 r;
#pragma unroll
            for (int j = 0; j < 8; ++j) {
                float t = (float)bs[kt][j] + (float)bd[kt][j];
                r[j] = (__bf16)(t > 0.f ? t : 0.f);
            }
            a2[kt] = r;
        }
        // buffer now dead: issue next tile's gathers, in flight across GEMM + epilogue
        if (ti + 1 < 4) {
            const u16* ps = gh + se[ti + 1] * DH + q * 8;
            const u16* pd = gh + de[ti + 1] * DH + q * 8;
#pragma unroll
            for (int kt = 0; kt < 4; ++kt) {
                bs[kt] = *(const bf16x8*)(ps + kt * 32);
                bd[kt] = *(const bf16x8*)(pd + kt * 32);
            }
        }
        f32x4 acc2[8];
#pragma unroll
        for (int nt = 0; nt < 8; ++nt) acc2[nt] = z;
#pragma unroll
        for (int kt = 0; kt < 4; ++kt)
#pragma unroll
            for (int nt = 0; nt < 8; ++nt) {
                bf16x8 b = *(const bf16x8*)(wlds + (kt * 8 + nt) * 512 + lane * 8);
                acc2[nt] = mfma16(a2[kt], b, acc2[nt]);
            }
        // out layer + log_softmax
#pragma unroll
        for (int rg = 0; rg < 4; ++rg) {
            float p0 = 0.f, p1 = 0.f;
#pragma unroll
            for (int nt = 0; nt < 8; ++nt) {
                float t = acc2[nt][rg] + bb2[nt];
                t = t > 0.f ? t : 0.f;
                p0 += t * owp0[nt];
                p1 += t * owp1[nt];
            }
#pragma unroll
            for (int m = 1; m < 16; m <<= 1) {
                p0 += __shfl_xor(p0, m, 64);
                p1 += __shfl_xor(p1, m, 64);
            }
            if (l15 == 0) {
                int e = eBase + ti * 16 + q * 4 + rg;
                float s0 = p0 + ob0, s1 = p1 + ob1;
                float mx = fmaxf(s0, s1);
                float lse = mx + __logf(__expf(s0 - mx) + __expf(s1 - mx));
                outp[e] = make_float2(s0 - lse, s1 - lse);
            }
        }
    }
}

extern "C" void kernel_launch(void* const* d_in, const int* in_sizes, int n_in,
                              void* d_out, int out_size, void* d_ws, size_t ws_size,
                              hipStream_t stream) {
    const float* x  = (const float*)d_in[0];
    const int* ei   = (const int*)d_in[1];
    const float* wg = (const float*)d_in[2];
    const float* bg = (const float*)d_in[3];
    const float* w1 = (const float*)d_in[4];
    const float* b1 = (const float*)d_in[5];
    const float* w2 = (const float*)d_in[6];
    const float* b2 = (const float*)d_in[7];
    const float* ow = (const float*)d_in[8];
    const float* ob = (const float*)d_in[9];
    float2* out = (float2*)d_out;

    char* ws = (char*)d_ws;
    size_t off = 0;
    auto alloc = [&](size_t bytes) { void* p = ws + off; off += (bytes + 255) & ~(size_t)255; return p; };
    u16* h0      = (u16*)alloc((size_t)NN * DH * 2);   // x@Wg (unscaled), gather source
    u16* ghb     = (u16*)alloc((size_t)NN * DH * 2);   // gh output (h0 stays live during fused kernel)
    int* bucket  = (int*)alloc((size_t)NN * BCAP * 4);
    int* cnt     = (int*)alloc((size_t)NN * 4);
    u16* w12f    = (u16*)alloc(65536);
    u16* wgf     = (u16*)alloc(65536);

    hipMemsetAsync(cnt, 0, (size_t)NN * 4, stream);
    k_prep_gemm<<<GEMM_BLKS + SWZ_BLKS + FILL_BLKS, 256, 0, stream>>>(
        x, w1, w2, wg, w12f, wgf, ei, cnt, bucket, h0);
    k_agg_mlp<<<(NN + 63) / 64, 256, 0, stream>>>(h0, cnt, bucket, bg, w12f, b1, b2, ghb);
    k_edge_mlp<<<NE / 256, 256, 0, stream>>>(ghb, ei, w12f, b2, ow, ob, out);
}